// Round 15
// baseline (113.889 us; speedup 1.0000x reference)
//
#include <hip/hip_runtime.h>

typedef __attribute__((ext_vector_type(4))) float f32x4;
typedef __attribute__((ext_vector_type(8))) short s16x8;

#define DEV __device__ __forceinline__

namespace {
constexpr int CH = 128;    // C == D
constexpr int TDIM = 512;  // T
constexpr int NBLK = 512;  // phase grid size (whole grid resident)
constexpr float INV_ROWS = 1.0f / 65536.0f;  // N*T
constexpr float EPS = 1e-5f;

DEV unsigned short f2bf(float f) {  // RNE (init paths only)
  unsigned int u = __float_as_uint(f);
  u = (u + 0x7FFFu + ((u >> 16) & 1u)) >> 16;
  return (unsigned short)u;
}
DEV float bf2f(unsigned short s) { return __uint_as_float(((unsigned int)s) << 16); }

// half-up-rounded bf16 pair pack (validated r7-r14: absmax 0.03125)
DEV unsigned int pack2bf(float lo, float hi) {
  unsigned int ua = __float_as_uint(lo) + 0x8000u;
  unsigned int ub = __float_as_uint(hi) + 0x8000u;
#if __has_builtin(__builtin_amdgcn_perm)
  return __builtin_amdgcn_perm(ub, ua, 0x07060302u);
#else
  return (ub & 0xFFFF0000u) | (ua >> 16);
#endif
}

// LDS-only barrier (T4): ds_writes made visible WITHOUT draining vmcnt.
// __syncthreads() emits s_waitcnt vmcnt(0) lgkmcnt(0) before s_barrier, which
// drains the distance-2 LOADT prefetch every tile. Correctness: all cross-wave
// hazards here are LDS (xg/raw), covered by lgkmcnt(0)+barrier; global loads
// are same-thread consumed (compiler inserts counted vmcnt at use).
// Mechanism correctness-validated in r9 (identical absmax).
DEV void lds_barrier() {
  asm volatile("s_waitcnt lgkmcnt(0)" ::: "memory");
  __builtin_amdgcn_s_barrier();
  asm volatile("" ::: "memory");
}

// tanh(x)+1 == 2/(1+e^(-2x)); exact 1.0 at x==0.
DEV float maskval(float x) { return 2.0f / (1.0f + __expf(-2.0f * x)); }

// gathered/masked tile, bf16, buf[2] x [v][t(16)][c(128)], XOR swizzle on c
DEV int xgi(int b, int v, int t, int c) {
  return (((b << 2) + v) * 16 + t) * 128 + (c ^ ((t & 7) << 3));
}
// raw x tile, bf16, buf[2] x [c(128)][t(16)][v(4)], XOR swizzle on t*4
DEV int rawi(int b, int c, int t) {
  return b * 8192 + c * 64 + ((t * 4) ^ ((c & 7) << 3));
}
}  // namespace

// PHASE 1: stage gathered/masked bf16 x-tile -> LDS, MFMA o = xg @ W, accumulate
//          per-column sum(o^2) + raw-x column sums in regs; per-block partials
//          to distinct addresses (no contended atomics).
// PHASE 2: recompute o, BN affine from tab (shift_out gathered register-locally),
//          residual from the raw-bf16 LDS copy of the SAME tile (no global
//          re-read), ReLU, coalesced f32x4 store.
// r11 structure + lgkm-only barriers (prefetch survives tile boundaries).
template <int PHASE>
__global__ __launch_bounds__(512) void gcn_fused(
    const float* __restrict__ x, const float* __restrict__ W,
    const float* __restrict__ FM, const int* __restrict__ shin,
    const int* __restrict__ shout, const float* __restrict__ tab,
    float* __restrict__ part, float* __restrict__ out) {
  __shared__ __align__(16) unsigned short xg[2 * 4 * 16 * 128];  // 32 KB dbuf
  __shared__ __align__(16) unsigned short raw[2 * 128 * 16 * 4]; // 32 KB dbuf (P2)

  const int tid = threadIdx.x;
  const int lane = tid & 63;
  const int w = tid >> 6;     // 8 waves
  const int g4 = lane >> 4;   // k-group (B) / d-subrow group (C)
  const int l16 = lane & 15;  // t column
  const int dbase = w * 16;   // wave owns 16 d

  const int bid = blockIdx.x;      // 512 blocks
  const int n = bid >> 2;          // batch index
  const int tb = (bid & 3) * 128;  // 128 t per block, 8 tiles of 16

  // staging mapping: thread owns channel pair (c0,c0+1), t = tlow + 8*h
  const int tlow = tid & 7;
  const int c0 = (tid >> 3) * 2;

  // per-thread gather constants (shift preserves channel: src = sv*128 + c)
  float mk[2][4];
  unsigned int svp = 0;
#pragma unroll
  for (int i = 0; i < 2; ++i)
#pragma unroll
    for (int v = 0; v < 4; ++v) {
      int j = v * CH + (c0 + i);
      mk[i][v] = maskval(FM[j]);
      svp |= (unsigned int)((shin[j] >> 7) & 3) << ((i * 4 + v) * 2);
    }

  // W^T A-fragments: rows d = dbase + l16, k = kk*32 + g4*8 + e
  s16x8 wt[4];
#pragma unroll
  for (int kk = 0; kk < 4; ++kk) {
    s16x8 f;
#pragma unroll
    for (int e = 0; e < 8; ++e)
      f[e] = (short)f2bf(W[(kk * 32 + g4 * 8 + e) * CH + dbase + l16]);
    wt[kk] = f;
  }

  // phase-2: packed shift_out selectors, one 2-bit field per (r,v)
  unsigned int svo = 0;
  if (PHASE == 2) {
#pragma unroll
    for (int r = 0; r < 4; ++r) {
      int d = dbase + g4 * 4 + r;
#pragma unroll
      for (int v = 0; v < 4; ++v)
        svo |= (unsigned int)((shout[v * CH + d] >> 7) & 3) << (r * 8 + v * 2);
    }
  }

  float s2[4][4];
  f32x4 rs[2];
  if (PHASE == 1) {
#pragma unroll
    for (int vo = 0; vo < 4; ++vo)
#pragma unroll
      for (int r = 0; r < 4; ++r) s2[vo][r] = 0.f;
    rs[0] = f32x4{0.f, 0.f, 0.f, 0.f};
    rs[1] = f32x4{0.f, 0.f, 0.f, 0.f};
  }

  const f32x4* xf4 = (const f32x4*)x;
  const float2* tab2 = (const float2*)tab;

  f32x4 pa[2][2], pb[2][2];  // distance-2 stage prefetch slots

#define LOADT(SLOT, TILE)                                                 \
  {                                                                       \
    _Pragma("unroll") for (int h = 0; h < 2; ++h) {                       \
      const int tgl = tb + (TILE) * 16 + h * 8 + tlow;                    \
      pa[SLOT][h] = xf4[(n * CH + c0) * TDIM + tgl];                      \
      pb[SLOT][h] = xf4[(n * CH + c0 + 1) * TDIM + tgl];                  \
    }                                                                     \
  }

#define STAGE(BUF, SLOT)                                                  \
  {                                                                       \
    _Pragma("unroll") for (int h = 0; h < 2; ++h) {                       \
      const int t = h * 8 + tlow;                                         \
      if (PHASE == 1) {                                                   \
        rs[0] += pa[SLOT][h];                                             \
        rs[1] += pb[SLOT][h];                                             \
      }                                                                   \
      if (PHASE == 2) { /* raw bf16 copy for the residual */              \
        uint2 u0, u1;                                                     \
        u0.x = pack2bf(pa[SLOT][h][0], pa[SLOT][h][1]);                   \
        u0.y = pack2bf(pa[SLOT][h][2], pa[SLOT][h][3]);                   \
        u1.x = pack2bf(pb[SLOT][h][0], pb[SLOT][h][1]);                   \
        u1.y = pack2bf(pb[SLOT][h][2], pb[SLOT][h][3]);                   \
        *(uint2*)&raw[rawi(BUF, c0, t)] = u0;                             \
        *(uint2*)&raw[rawi(BUF, c0 + 1, t)] = u1;                         \
      }                                                                   \
      _Pragma("unroll") for (int v = 0; v < 4; ++v) {                     \
        int s0 = (svp >> ((0 * 4 + v) * 2)) & 3;                          \
        float a = pa[SLOT][h][0];                                         \
        a = (s0 == 1) ? pa[SLOT][h][1] : a;                               \
        a = (s0 == 2) ? pa[SLOT][h][2] : a;                               \
        a = (s0 == 3) ? pa[SLOT][h][3] : a;                               \
        a *= mk[0][v];                                                    \
        int s1 = (svp >> ((1 * 4 + v) * 2)) & 3;                          \
        float b = pb[SLOT][h][0];                                         \
        b = (s1 == 1) ? pb[SLOT][h][1] : b;                               \
        b = (s1 == 2) ? pb[SLOT][h][2] : b;                               \
        b = (s1 == 3) ? pb[SLOT][h][3] : b;                               \
        b *= mk[1][v];                                                    \
        *(unsigned int*)&xg[xgi(BUF, v, t, c0)] = pack2bf(a, b);          \
      }                                                                   \
    }                                                                     \
  }

  {  // prologue: fill both stage slots, stage tile 0
    LOADT(0, 0)
    LOADT(1, 1)
    STAGE(0, 0)
  }

#pragma unroll
  for (int tile = 0; tile < 8; ++tile) {
    const int buf = tile & 1;
    lds_barrier();  // buf writes visible; prefetch stays in flight

    // issue stage loads for tile+2 (consumed by STAGE at end of NEXT iter)
    if (tile < 6) LOADT(buf, tile + 2)

    // ---- MFMA: o[d][t] = sum_c W[c][d] * xg[vo][t][c] ----
    f32x4 acc[4];
    const f32x4 z4 = {0.f, 0.f, 0.f, 0.f};
#pragma unroll
    for (int vo = 0; vo < 4; ++vo) acc[vo] = z4;
#pragma unroll
    for (int vo = 0; vo < 4; ++vo) {
      s16x8 bfr[4];
#pragma unroll
      for (int kk = 0; kk < 4; ++kk)
        bfr[kk] = *(const s16x8*)&xg[xgi(buf, vo, l16, kk * 32 + g4 * 8)];
#pragma unroll
      for (int kk = 0; kk < 4; ++kk)
        acc[vo] = __builtin_amdgcn_mfma_f32_16x16x32_bf16(wt[kk], bfr[kk], acc[vo], 0, 0, 0);
    }

    if (PHASE == 1) {
#pragma unroll
      for (int vo = 0; vo < 4; ++vo)
#pragma unroll
        for (int r = 0; r < 4; ++r) s2[vo][r] = fmaf(acc[vo][r], acc[vo][r], s2[vo][r]);
    } else {
      // ---- epilogue: shift_out select + BN affine + LDS residual + ReLU ----
      const int tg = tb + tile * 16 + l16;
#pragma unroll
      for (int r = 0; r < 4; ++r) {
        const int d = dbase + g4 * 4 + r;
        const uint2 rv = *(const uint2*)&raw[rawi(buf, d, l16)];
        f32x4 o;
#pragma unroll
        for (int v = 0; v < 4; ++v) {
          int sv = (svo >> (r * 8 + v * 2)) & 3;
          float ov = acc[0][r];
          ov = (sv == 1) ? acc[1][r] : ov;
          ov = (sv == 2) ? acc[2][r] : ov;
          ov = (sv == 3) ? acc[3][r] : ov;
          float2 ssv = tab2[v * CH + d];
          unsigned int rw = (v < 2) ? rv.x : rv.y;
          float res = bf2f((unsigned short)((v & 1) ? (rw >> 16) : (rw & 0xFFFFu)));
          float y = fmaf(ov, ssv.x, ssv.y) + res;
          o[v] = fmaxf(y, 0.f);
        }
        *(f32x4*)&out[((n * CH + d) * TDIM + tg) * 4] = o;
      }
    }

    // stage tile t+1 from the other slot (loads in flight since iter t-1;
    // counted vmcnt wait at use, not a full drain)
    if (tile < 7) STAGE(buf ^ 1, buf ^ 1)
  }
#undef STAGE
#undef LOADT

  if (PHASE == 1) {
    // per-block partials to DISTINCT addresses: part[row][bid]
#pragma unroll
    for (int vo = 0; vo < 4; ++vo)
#pragma unroll
      for (int r = 0; r < 4; ++r) {
        float v = s2[vo][r];
        v += __shfl_xor(v, 1, 64);
        v += __shfl_xor(v, 2, 64);
        v += __shfl_xor(v, 4, 64);
        v += __shfl_xor(v, 8, 64);
        if (l16 == 0) part[(vo * CH + dbase + g4 * 4 + r) * NBLK + bid] = v;
      }
#pragma unroll
    for (int i = 0; i < 2; ++i)
#pragma unroll
      for (int v = 0; v < 4; ++v) {
        float vv = rs[i][v];
        vv += __shfl_xor(vv, 1, 64);
        vv += __shfl_xor(vv, 2, 64);
        vv += __shfl_xor(vv, 4, 64);
        if (tlow == 0) part[(512 + (c0 + i) * 4 + v) * NBLK + bid] = vv;
      }
  }
}

// Sum the NBLK per-block partials for each of the 1024 rows (coalesced).
__global__ __launch_bounds__(256) void gcn_reduce(const float* __restrict__ part,
                                                  float* __restrict__ sums) {
  __shared__ float acc4[4];
  const int r = blockIdx.x;
  const int t = threadIdx.x;
  const float* row = part + r * NBLK;
  float s = row[t] + row[t + 256];
#pragma unroll
  for (int off = 1; off < 64; off <<= 1) s += __shfl_xor(s, off, 64);
  if ((t & 63) == 0) acc4[t >> 6] = s;
  __syncthreads();
  if (t == 0) sums[r] = acc4[0] + acc4[1] + acc4[2] + acc4[3];
}

// mean via W^T @ (mask * gathered raw column sums); var from sum(o^2);
// then per-output-column affine via shift_out. (Linear_bias cancels in
// training-mode BatchNorm -> omitted throughout.)
__global__ void gcn_finalize(const float* __restrict__ sums,
                             const float* __restrict__ W,
                             const float* __restrict__ FM,
                             const int* __restrict__ shin,
                             const int* __restrict__ shout,
                             const float* __restrict__ gamma,
                             const float* __restrict__ beta,
                             float* __restrict__ tab) {
  __shared__ float q[512];
  __shared__ float meanS[512];
  __shared__ float rstdS[512];
  const int j = threadIdx.x;  // j = vo*128 + (c or d)
  const int vo = j >> 7;
  const int c = j & 127;
  const int sv = (shin[j] >> 7) & 3;
  q[j] = maskval(FM[j]) * sums[512 + c * 4 + sv];  // raw-x sums rows
  __syncthreads();
  const int d = c;
  float acc = 0.f;
#pragma unroll 8
  for (int cc = 0; cc < 128; ++cc) acc = fmaf(W[cc * CH + d], q[vo * CH + cc], acc);
  const float mean = acc * INV_ROWS;
  const float var = sums[j] * INV_ROWS - mean * mean;  // sum(o^2) rows
  meanS[j] = mean;
  rstdS[j] = rsqrtf(var + EPS);
  __syncthreads();
  const int so = shout[j];
  const float sc = rstdS[so] * gamma[j];
  const float sh = beta[j] - meanS[so] * sc;
  tab[2 * j] = sc;
  tab[2 * j + 1] = sh;
}

extern "C" void kernel_launch(void* const* d_in, const int* in_sizes, int n_in,
                              void* d_out, int out_size, void* d_ws, size_t ws_size,
                              hipStream_t stream) {
  const float* x = (const float*)d_in[0];
  const float* W = (const float*)d_in[1];
  // d_in[2] = Linear_bias: cancels in training-mode BatchNorm, unused
  const float* FM = (const float*)d_in[3];
  const float* gamma = (const float*)d_in[4];
  const float* beta = (const float*)d_in[5];
  const int* shin = (const int*)d_in[6];
  const int* shout = (const int*)d_in[7];
  float* out = (float*)d_out;

  float* part = (float*)d_ws;        // [0, 1024*NBLK): per-block partials
  float* sums = part + 1024 * NBLK;  // [.., +1024): reduced sums
  float* tab = sums + 1024;          // [.., +1024): (scale,shift) per column

  gcn_fused<1><<<dim3(NBLK), dim3(512), 0, stream>>>(x, W, FM, shin, shout, tab, part, out);
  gcn_reduce<<<dim3(1024), dim3(256), 0, stream>>>(part, sums);
  gcn_finalize<<<dim3(1), dim3(512), 0, stream>>>(sums, W, FM, shin, shout, gamma, beta, tab);
  gcn_fused<2><<<dim3(NBLK), dim3(512), 0, stream>>>(x, W, FM, shin, shout, tab, part, out);
}

// Round 16
// 95.036 us; speedup vs baseline: 1.1984x; 1.1984x over previous
//
#include <hip/hip_runtime.h>

typedef __attribute__((ext_vector_type(4))) float f32x4;
typedef __attribute__((ext_vector_type(8))) short s16x8;

#define DEV __device__ __forceinline__

namespace {
constexpr int CH = 128;    // C == D
constexpr int TDIM = 512;  // T
constexpr int NBLK = 512;  // phase grid size (whole grid resident)
constexpr float INV_ROWS = 1.0f / 65536.0f;  // N*T
constexpr float EPS = 1e-5f;

DEV unsigned short f2bf(float f) {  // RNE (init paths only)
  unsigned int u = __float_as_uint(f);
  u = (u + 0x7FFFu + ((u >> 16) & 1u)) >> 16;
  return (unsigned short)u;
}
DEV float bf2f(unsigned short s) { return __uint_as_float(((unsigned int)s) << 16); }

// half-up-rounded bf16 pair pack (validated r7-r15: absmax 0.03125)
DEV unsigned int pack2bf(float lo, float hi) {
  unsigned int ua = __float_as_uint(lo) + 0x8000u;
  unsigned int ub = __float_as_uint(hi) + 0x8000u;
#if __has_builtin(__builtin_amdgcn_perm)
  return __builtin_amdgcn_perm(ub, ua, 0x07060302u);
#else
  return (ub & 0xFFFF0000u) | (ua >> 16);
#endif
}

// tanh(x)+1 == 2/(1+e^(-2x)); exact 1.0 at x==0.
DEV float maskval(float x) { return 2.0f / (1.0f + __expf(-2.0f * x)); }

// gathered/masked tile, bf16, buf[2] x [v][t(16)][c(128)], XOR swizzle on c
DEV int xgi(int b, int v, int t, int c) {
  return (((b << 2) + v) * 16 + t) * 128 + (c ^ ((t & 7) << 3));
}
// raw x tile, bf16, buf[2] x [c(128)][t(16)][v(4)], XOR swizzle on t*4
DEV int rawi(int b, int c, int t) {
  return b * 8192 + c * 64 + ((t * 4) ^ ((c & 7) << 3));
}
}  // namespace

// PHASE 1: stage gathered/masked bf16 x-tile -> LDS, MFMA o = xg @ W, accumulate
//          per-column sum(o^2) + raw-x column sums in regs; per-block partials
//          to distinct addresses (no contended atomics).
// PHASE 2: recompute o, BN affine from tab (shift_out gathered register-locally),
//          residual from the raw-bf16 LDS copy of the SAME tile (no global
//          re-read), ReLU, coalesced f32x4 store.
// r5 skeleton: 512 blocks x 8 tiles, stage prefetch distance 2, one
// __syncthreads per tile, STAGE at iteration bottom.  (r11/r14 exact -
// validated best: 95.3/95.75 us. lgkm-only barrier variant REGRESSED (r15:
// 113.9) - plain __syncthreads lets the compiler schedule the region.)
template <int PHASE>
__global__ __launch_bounds__(512) void gcn_fused(
    const float* __restrict__ x, const float* __restrict__ W,
    const float* __restrict__ FM, const int* __restrict__ shin,
    const int* __restrict__ shout, const float* __restrict__ tab,
    float* __restrict__ part, float* __restrict__ out) {
  __shared__ __align__(16) unsigned short xg[2 * 4 * 16 * 128];  // 32 KB dbuf
  __shared__ __align__(16) unsigned short raw[2 * 128 * 16 * 4]; // 32 KB dbuf (P2)

  const int tid = threadIdx.x;
  const int lane = tid & 63;
  const int w = tid >> 6;     // 8 waves
  const int g4 = lane >> 4;   // k-group (B) / d-subrow group (C)
  const int l16 = lane & 15;  // t column
  const int dbase = w * 16;   // wave owns 16 d

  const int bid = blockIdx.x;      // 512 blocks
  const int n = bid >> 2;          // batch index
  const int tb = (bid & 3) * 128;  // 128 t per block, 8 tiles of 16

  // staging mapping: thread owns channel pair (c0,c0+1), t = tlow + 8*h
  const int tlow = tid & 7;
  const int c0 = (tid >> 3) * 2;

  // per-thread gather constants (shift preserves channel: src = sv*128 + c)
  float mk[2][4];
  unsigned int svp = 0;
#pragma unroll
  for (int i = 0; i < 2; ++i)
#pragma unroll
    for (int v = 0; v < 4; ++v) {
      int j = v * CH + (c0 + i);
      mk[i][v] = maskval(FM[j]);
      svp |= (unsigned int)((shin[j] >> 7) & 3) << ((i * 4 + v) * 2);
    }

  // W^T A-fragments: rows d = dbase + l16, k = kk*32 + g4*8 + e
  s16x8 wt[4];
#pragma unroll
  for (int kk = 0; kk < 4; ++kk) {
    s16x8 f;
#pragma unroll
    for (int e = 0; e < 8; ++e)
      f[e] = (short)f2bf(W[(kk * 32 + g4 * 8 + e) * CH + dbase + l16]);
    wt[kk] = f;
  }

  // phase-2: packed shift_out selectors, one 2-bit field per (r,v)
  unsigned int svo = 0;
  if (PHASE == 2) {
#pragma unroll
    for (int r = 0; r < 4; ++r) {
      int d = dbase + g4 * 4 + r;
#pragma unroll
      for (int v = 0; v < 4; ++v)
        svo |= (unsigned int)((shout[v * CH + d] >> 7) & 3) << (r * 8 + v * 2);
    }
  }

  float s2[4][4];
  f32x4 rs[2];
  if (PHASE == 1) {
#pragma unroll
    for (int vo = 0; vo < 4; ++vo)
#pragma unroll
      for (int r = 0; r < 4; ++r) s2[vo][r] = 0.f;
    rs[0] = f32x4{0.f, 0.f, 0.f, 0.f};
    rs[1] = f32x4{0.f, 0.f, 0.f, 0.f};
  }

  const f32x4* xf4 = (const f32x4*)x;
  const float2* tab2 = (const float2*)tab;

  f32x4 pa[2][2], pb[2][2];  // distance-2 stage prefetch slots

#define LOADT(SLOT, TILE)                                                 \
  {                                                                       \
    _Pragma("unroll") for (int h = 0; h < 2; ++h) {                       \
      const int tgl = tb + (TILE) * 16 + h * 8 + tlow;                    \
      pa[SLOT][h] = xf4[(n * CH + c0) * TDIM + tgl];                      \
      pb[SLOT][h] = xf4[(n * CH + c0 + 1) * TDIM + tgl];                  \
    }                                                                     \
  }

#define STAGE(BUF, SLOT)                                                  \
  {                                                                       \
    _Pragma("unroll") for (int h = 0; h < 2; ++h) {                       \
      const int t = h * 8 + tlow;                                         \
      if (PHASE == 1) {                                                   \
        rs[0] += pa[SLOT][h];                                             \
        rs[1] += pb[SLOT][h];                                             \
      }                                                                   \
      if (PHASE == 2) { /* raw bf16 copy for the residual */              \
        uint2 u0, u1;                                                     \
        u0.x = pack2bf(pa[SLOT][h][0], pa[SLOT][h][1]);                   \
        u0.y = pack2bf(pa[SLOT][h][2], pa[SLOT][h][3]);                   \
        u1.x = pack2bf(pb[SLOT][h][0], pb[SLOT][h][1]);                   \
        u1.y = pack2bf(pb[SLOT][h][2], pb[SLOT][h][3]);                   \
        *(uint2*)&raw[rawi(BUF, c0, t)] = u0;                             \
        *(uint2*)&raw[rawi(BUF, c0 + 1, t)] = u1;                         \
      }                                                                   \
      _Pragma("unroll") for (int v = 0; v < 4; ++v) {                     \
        int s0 = (svp >> ((0 * 4 + v) * 2)) & 3;                          \
        float a = pa[SLOT][h][0];                                         \
        a = (s0 == 1) ? pa[SLOT][h][1] : a;                               \
        a = (s0 == 2) ? pa[SLOT][h][2] : a;                               \
        a = (s0 == 3) ? pa[SLOT][h][3] : a;                               \
        a *= mk[0][v];                                                    \
        int s1 = (svp >> ((1 * 4 + v) * 2)) & 3;                          \
        float b = pb[SLOT][h][0];                                         \
        b = (s1 == 1) ? pb[SLOT][h][1] : b;                               \
        b = (s1 == 2) ? pb[SLOT][h][2] : b;                               \
        b = (s1 == 3) ? pb[SLOT][h][3] : b;                               \
        b *= mk[1][v];                                                    \
        *(unsigned int*)&xg[xgi(BUF, v, t, c0)] = pack2bf(a, b);          \
      }                                                                   \
    }                                                                     \
  }

  {  // prologue: fill both stage slots, stage tile 0
    LOADT(0, 0)
    LOADT(1, 1)
    STAGE(0, 0)
  }

#pragma unroll
  for (int tile = 0; tile < 8; ++tile) {
    const int buf = tile & 1;
    __syncthreads();  // buf writes visible

    // issue stage loads for tile+2 (consumed by STAGE at end of NEXT iter)
    if (tile < 6) LOADT(buf, tile + 2)

    // ---- MFMA: o[d][t] = sum_c W[c][d] * xg[vo][t][c] ----
    f32x4 acc[4];
    const f32x4 z4 = {0.f, 0.f, 0.f, 0.f};
#pragma unroll
    for (int vo = 0; vo < 4; ++vo) acc[vo] = z4;
#pragma unroll
    for (int vo = 0; vo < 4; ++vo) {
      s16x8 bfr[4];
#pragma unroll
      for (int kk = 0; kk < 4; ++kk)
        bfr[kk] = *(const s16x8*)&xg[xgi(buf, vo, l16, kk * 32 + g4 * 8)];
#pragma unroll
      for (int kk = 0; kk < 4; ++kk)
        acc[vo] = __builtin_amdgcn_mfma_f32_16x16x32_bf16(wt[kk], bfr[kk], acc[vo], 0, 0, 0);
    }

    if (PHASE == 1) {
#pragma unroll
      for (int vo = 0; vo < 4; ++vo)
#pragma unroll
        for (int r = 0; r < 4; ++r) s2[vo][r] = fmaf(acc[vo][r], acc[vo][r], s2[vo][r]);
    } else {
      // ---- epilogue: shift_out select + BN affine + LDS residual + ReLU ----
      const int tg = tb + tile * 16 + l16;
#pragma unroll
      for (int r = 0; r < 4; ++r) {
        const int d = dbase + g4 * 4 + r;
        const uint2 rv = *(const uint2*)&raw[rawi(buf, d, l16)];
        f32x4 o;
#pragma unroll
        for (int v = 0; v < 4; ++v) {
          int sv = (svo >> (r * 8 + v * 2)) & 3;
          float ov = acc[0][r];
          ov = (sv == 1) ? acc[1][r] : ov;
          ov = (sv == 2) ? acc[2][r] : ov;
          ov = (sv == 3) ? acc[3][r] : ov;
          float2 ssv = tab2[v * CH + d];
          unsigned int rw = (v < 2) ? rv.x : rv.y;
          float res = bf2f((unsigned short)((v & 1) ? (rw >> 16) : (rw & 0xFFFFu)));
          float y = fmaf(ov, ssv.x, ssv.y) + res;
          o[v] = fmaxf(y, 0.f);
        }
        *(f32x4*)&out[((n * CH + d) * TDIM + tg) * 4] = o;
      }
    }

    // stage tile t+1 from the other slot (loads in flight since iter t-1)
    if (tile < 7) STAGE(buf ^ 1, buf ^ 1)
  }
#undef STAGE
#undef LOADT

  if (PHASE == 1) {
    // per-block partials to DISTINCT addresses: part[row][bid]
#pragma unroll
    for (int vo = 0; vo < 4; ++vo)
#pragma unroll
      for (int r = 0; r < 4; ++r) {
        float v = s2[vo][r];
        v += __shfl_xor(v, 1, 64);
        v += __shfl_xor(v, 2, 64);
        v += __shfl_xor(v, 4, 64);
        v += __shfl_xor(v, 8, 64);
        if (l16 == 0) part[(vo * CH + dbase + g4 * 4 + r) * NBLK + bid] = v;
      }
#pragma unroll
    for (int i = 0; i < 2; ++i)
#pragma unroll
      for (int v = 0; v < 4; ++v) {
        float vv = rs[i][v];
        vv += __shfl_xor(vv, 1, 64);
        vv += __shfl_xor(vv, 2, 64);
        vv += __shfl_xor(vv, 4, 64);
        if (tlow == 0) part[(512 + (c0 + i) * 4 + v) * NBLK + bid] = vv;
      }
  }
}

// Sum the NBLK per-block partials for each of the 1024 rows (coalesced).
__global__ __launch_bounds__(256) void gcn_reduce(const float* __restrict__ part,
                                                  float* __restrict__ sums) {
  __shared__ float acc4[4];
  const int r = blockIdx.x;
  const int t = threadIdx.x;
  const float* row = part + r * NBLK;
  float s = row[t] + row[t + 256];
#pragma unroll
  for (int off = 1; off < 64; off <<= 1) s += __shfl_xor(s, off, 64);
  if ((t & 63) == 0) acc4[t >> 6] = s;
  __syncthreads();
  if (t == 0) sums[r] = acc4[0] + acc4[1] + acc4[2] + acc4[3];
}

// mean via W^T @ (mask * gathered raw column sums); var from sum(o^2);
// then per-output-column affine via shift_out. (Linear_bias cancels in
// training-mode BatchNorm -> omitted throughout.)
__global__ void gcn_finalize(const float* __restrict__ sums,
                             const float* __restrict__ W,
                             const float* __restrict__ FM,
                             const int* __restrict__ shin,
                             const int* __restrict__ shout,
                             const float* __restrict__ gamma,
                             const float* __restrict__ beta,
                             float* __restrict__ tab) {
  __shared__ float q[512];
  __shared__ float meanS[512];
  __shared__ float rstdS[512];
  const int j = threadIdx.x;  // j = vo*128 + (c or d)
  const int vo = j >> 7;
  const int c = j & 127;
  const int sv = (shin[j] >> 7) & 3;
  q[j] = maskval(FM[j]) * sums[512 + c * 4 + sv];  // raw-x sums rows
  __syncthreads();
  const int d = c;
  float acc = 0.f;
#pragma unroll 8
  for (int cc = 0; cc < 128; ++cc) acc = fmaf(W[cc * CH + d], q[vo * CH + cc], acc);
  const float mean = acc * INV_ROWS;
  const float var = sums[j] * INV_ROWS - mean * mean;  // sum(o^2) rows
  meanS[j] = mean;
  rstdS[j] = rsqrtf(var + EPS);
  __syncthreads();
  const int so = shout[j];
  const float sc = rstdS[so] * gamma[j];
  const float sh = beta[j] - meanS[so] * sc;
  tab[2 * j] = sc;
  tab[2 * j + 1] = sh;
}

extern "C" void kernel_launch(void* const* d_in, const int* in_sizes, int n_in,
                              void* d_out, int out_size, void* d_ws, size_t ws_size,
                              hipStream_t stream) {
  const float* x = (const float*)d_in[0];
  const float* W = (const float*)d_in[1];
  // d_in[2] = Linear_bias: cancels in training-mode BatchNorm, unused
  const float* FM = (const float*)d_in[3];
  const float* gamma = (const float*)d_in[4];
  const float* beta = (const float*)d_in[5];
  const int* shin = (const int*)d_in[6];
  const int* shout = (const int*)d_in[7];
  float* out = (float*)d_out;

  float* part = (float*)d_ws;        // [0, 1024*NBLK): per-block partials
  float* sums = part + 1024 * NBLK;  // [.., +1024): reduced sums
  float* tab = sums + 1024;          // [.., +1024): (scale,shift) per column

  gcn_fused<1><<<dim3(NBLK), dim3(512), 0, stream>>>(x, W, FM, shin, shout, tab, part, out);
  gcn_reduce<<<dim3(1024), dim3(256), 0, stream>>>(part, sums);
  gcn_finalize<<<dim3(1), dim3(512), 0, stream>>>(sums, W, FM, shin, shout, gamma, beta, tab);
  gcn_fused<2><<<dim3(NBLK), dim3(512), 0, stream>>>(x, W, FM, shin, shout, tab, part, out);
}